// Round 1
// 138.466 us; speedup vs baseline: 1.0001x; 1.0001x over previous
//
#include <hip/hip_runtime.h>
#include <stdint.h>

#define NXS 8192
#define HS  1024

typedef __attribute__((ext_vector_type(8))) short short8;
typedef __attribute__((ext_vector_type(4))) float f32x4;

__device__ __forceinline__ float bf2f(uint32_t b) {
    union { uint32_t u; float f; } c; c.u = b << 16; return c.f;
}
__device__ __forceinline__ uint16_t f2bf(float f) {
    union { float f; uint32_t u; } c; c.f = f;
    return (uint16_t)((c.u + 0x7fffu + ((c.u >> 16) & 1u)) >> 16);
}
__device__ __forceinline__ void async_cp16(const void* g, void* l) {
    __builtin_amdgcn_global_load_lds(
        (const __attribute__((address_space(1))) void*)g,
        (__attribute__((address_space(3))) void*)l,
        16, 0, 0);
}

// ---- K01: merged prep (unchanged) ----
// [0,1024):     Z1 = tanh(x@W1^T+b1), 8 samples/block
// [1024,1536):  pack Bp1[g][c][lane][8] = bf16 W2[g*16+lr][c*32+lq*8+j]
// [1536,2048):  pack Bp2[g][c][lane][8] = bf16 W2[c*32+lq*8+j][g*16+lr]
// [2048,2336):  init out: y = b3, dydx = 0
// [2336,2400):  W1T[16][1024] bf16 (rows 8..15 zero)
__global__ __launch_bounds__(256) void k01(
    const float* __restrict__ x, const float* __restrict__ W1,
    const float* __restrict__ b1, const float* __restrict__ W2,
    const float* __restrict__ b3, uint16_t* __restrict__ Z1,
    uint16_t* __restrict__ Bp1, uint16_t* __restrict__ Bp2,
    uint16_t* __restrict__ W1T, float* __restrict__ out)
{
    __shared__ float xs[8][8];
    const int b = blockIdx.x, t = threadIdx.x;
    if (b < 1024) {
        const int n0 = b * 8;
        if (t < 64) xs[t >> 3][t & 7] = x[n0 * 8 + t];
        const int j = t * 4;
        float w[4][8];
#pragma unroll
        for (int c = 0; c < 4; ++c) {
            float4 w0 = *(const float4*)(W1 + (j + c) * 8);
            float4 w1 = *(const float4*)(W1 + (j + c) * 8 + 4);
            w[c][0] = w0.x; w[c][1] = w0.y; w[c][2] = w0.z; w[c][3] = w0.w;
            w[c][4] = w1.x; w[c][5] = w1.y; w[c][6] = w1.z; w[c][7] = w1.w;
        }
        float4 bb = *(const float4*)(b1 + j);
        const float bv[4] = {bb.x, bb.y, bb.z, bb.w};
        __syncthreads();
#pragma unroll
        for (int s = 0; s < 8; ++s) {
            ushort4 o;
            uint16_t* op = (uint16_t*)&o;
#pragma unroll
            for (int c = 0; c < 4; ++c) {
                float sum = bv[c];
#pragma unroll
                for (int k = 0; k < 8; ++k) sum += xs[s][k] * w[c][k];
                op[c] = f2bf(tanhf(sum));
            }
            *(ushort4*)(Z1 + (size_t)(n0 + s) * HS + j) = o;
        }
    } else if (b < 1536) {
        const int tid = (b - 1024) * 256 + t;            // 0..131071
        const int l = tid & 63, c = (tid >> 6) & 31, g = tid >> 11;
        const int lr = l & 15, lq = l >> 4;
        const float* src = W2 + (size_t)(g * 16 + lr) * HS + c * 32 + lq * 8;
        float4 a0 = *(const float4*)src;
        float4 a1 = *(const float4*)(src + 4);
        uint16_t o[8];
        o[0] = f2bf(a0.x); o[1] = f2bf(a0.y); o[2] = f2bf(a0.z); o[3] = f2bf(a0.w);
        o[4] = f2bf(a1.x); o[5] = f2bf(a1.y); o[6] = f2bf(a1.z); o[7] = f2bf(a1.w);
        *(ushort4*)(Bp1 + (size_t)tid * 8)     = *(ushort4*)&o[0];
        *(ushort4*)(Bp1 + (size_t)tid * 8 + 4) = *(ushort4*)&o[4];
    } else if (b < 2048) {
        const int tid = (b - 1536) * 256 + t;
        const int l = tid & 63, c = (tid >> 6) & 31, g = tid >> 11;
        const int lr = l & 15, lq = l >> 4;
        uint16_t o[8];
#pragma unroll
        for (int j2 = 0; j2 < 8; ++j2)
            o[j2] = f2bf(W2[(size_t)(c * 32 + lq * 8 + j2) * HS + g * 16 + lr]);
        *(ushort4*)(Bp2 + (size_t)tid * 8)     = *(ushort4*)&o[0];
        *(ushort4*)(Bp2 + (size_t)tid * 8 + 4) = *(ushort4*)&o[4];
    } else if (b < 2336) {
        const int idx = (b - 2048) * 256 + t;            // 0..73727
        out[idx] = (idx < NXS) ? b3[0] : 0.f;
    } else {
        const int idx = (b - 2336) * 256 + t;            // 0..16383
        const int r = idx >> 10, cc = idx & 1023;
        W1T[idx] = (r < 8) ? f2bf(W1[cc * 8 + r]) : (uint16_t)0;
    }
}

// -------- GEMM: 128x128 tile, 4 waves (2x2), BK=64, A via LDS dbuf (xor-8
// swizzle over 128B rows -> conflict-free ds_read_b128), B direct-VGPR stream.
// Wave (wr,wc) owns rows [wr*64,+64) x cols [wc*64,+64): acc[4][4].
// 32 MFMA per wave per barrier interval (4x the old 64x128/BK=32 structure).
// MODE 0: C = Z1 @ W2^T (Bp1); epilogue: tanh -> V (bf16), y atomics
// MODE 1: C = U = V @ W2 (Bp2); fused MFMA dydx epilogue via W1T
template <int MODE>
__global__ __launch_bounds__(256, 2) void gemm_k(
    const uint16_t* __restrict__ A, const uint16_t* __restrict__ Bp,
    const float* __restrict__ bias, const float* __restrict__ W3,
    uint16_t* __restrict__ Out, float* __restrict__ yOut,
    const uint16_t* __restrict__ Z1, const uint16_t* __restrict__ W1T,
    float* __restrict__ dOut)
{
    // A dbuf: 2 x 16384 B at [0,32768). MODE1 epilogue c-matrix: 128x136 u16.
    constexpr int SMEM_U16 = (MODE == 1) ? 17408 : 16384;
    __shared__ __attribute__((aligned(16))) uint16_t smem[SMEM_U16];
    const int t = threadIdx.x;
    const int wave = t >> 6, lane = t & 63;
    const int lq = lane >> 4, lr = lane & 15;
    const int wr = wave >> 1, wc = wave & 1;
    const int rowBase = blockIdx.x * 128;
    const int colBase = blockIdx.y * 128;

    // A staging: 1024 segs of 16B per buffer (128 rows x 8 slots), 4/thread.
    // LDS dest linear (seg s at byte s*16); global source slot pre-swizzled
    // qA = (s&7)^(rA&7) so reads can un-swizzle -> 8 bank windows per quarter.
    const uint16_t* gA[4];
#pragma unroll
    for (int i = 0; i < 4; ++i) {
        int s = t + i * 256;
        int rA = s >> 3, qA = (s & 7) ^ (rA & 7);
        gA[i] = A + (size_t)(rowBase + rA) * HS + qA * 8;
    }

    // B fragment streams: wave wc owns groups colBase/16 + wc*4 + tj.
    // frag(g, chunk) at (g*32 + chunk)*512 + lane*8 u16; chunk = c*2+kk.
    const uint16_t* pB[4];
#pragma unroll
    for (int tj = 0; tj < 4; ++tj)
        pB[tj] = Bp + ((size_t)(colBase >> 4) + wc * 4 + tj) * 16384
                    + (size_t)lane * 8;

    f32x4 acc[4][4] = {};

    // prologue: stage K-step 0, preload its B frags
#pragma unroll
    for (int i = 0; i < 4; ++i)
        async_cp16(gA[i], (char*)smem + t * 16 + i * 4096);
    short8 bc[4][2];
#pragma unroll
    for (int tj = 0; tj < 4; ++tj) {
        bc[tj][0] = *(const short8*)(pB[tj]);
        bc[tj][1] = *(const short8*)(pB[tj] + 512);
    }
    __syncthreads();

    int buf = 0;
    for (int c = 0; c < 16; ++c) {
        short8 bn[4][2];
        if (c < 15) {
#pragma unroll
            for (int i = 0; i < 4; ++i)
                async_cp16(gA[i] + (c + 1) * 64,
                           (char*)smem + (buf ^ 1) * 16384 + t * 16 + i * 4096);
#pragma unroll
            for (int tj = 0; tj < 4; ++tj) {
                bn[tj][0] = *(const short8*)(pB[tj] + (c + 1) * 1024);
                bn[tj][1] = *(const short8*)(pB[tj] + (c + 1) * 1024 + 512);
            }
        }
        const uint16_t* pA = smem + buf * 8192;
#pragma unroll
        for (int kk = 0; kk < 2; ++kk) {
            short8 af[4];
#pragma unroll
            for (int ti = 0; ti < 4; ++ti) {
                int ar = wr * 64 + ti * 16 + lr;
                af[ti] = *(const short8*)(pA + ar * 64
                          + ((((kk << 2) + lq) ^ (ar & 7)) << 3));
            }
#pragma unroll
            for (int ti = 0; ti < 4; ++ti)
#pragma unroll
                for (int tj = 0; tj < 4; ++tj)
                    acc[ti][tj] = __builtin_amdgcn_mfma_f32_16x16x32_bf16(
                        af[ti], bc[tj][kk], acc[ti][tj], 0, 0, 0);
        }
        __syncthreads();
        if (c < 15) {
#pragma unroll
            for (int tj = 0; tj < 4; ++tj) {
                bc[tj][0] = bn[tj][0]; bc[tj][1] = bn[tj][1];
            }
        }
        buf ^= 1;
    }

    if (MODE == 0) {
        float cB[4], cW[4]; int cCol[4];
#pragma unroll
        for (int tj = 0; tj < 4; ++tj) {
            cCol[tj] = colBase + wc * 64 + tj * 16 + lr;
            cB[tj] = bias[cCol[tj]];
            cW[tj] = W3[cCol[tj]];
        }
#pragma unroll
        for (int ti = 0; ti < 4; ++ti) {
#pragma unroll
            for (int r = 0; r < 4; ++r) {
                int row = rowBase + wr * 64 + ti * 16 + lq * 4 + r;
                float ys = 0.f;
#pragma unroll
                for (int tj = 0; tj < 4; ++tj) {
                    float z2 = tanhf(acc[ti][tj][r] + cB[tj]);
                    ys += z2 * cW[tj];
                    Out[(size_t)row * HS + cCol[tj]] = f2bf((1.f - z2 * z2) * cW[tj]);
                }
                ys += __shfl_xor(ys, 1); ys += __shfl_xor(ys, 2);
                ys += __shfl_xor(ys, 4); ys += __shfl_xor(ys, 8);
                if (lr == 0) atomicAdd(&yOut[row], ys);
            }
        }
    } else {
        // c = U*(1-z1^2) -> LDS [128 rows][stride 136 u16]
#pragma unroll
        for (int ti = 0; ti < 4; ++ti)
#pragma unroll
            for (int r = 0; r < 4; ++r) {
                int rowl = wr * 64 + ti * 16 + lq * 4 + r;
                const size_t zrow = (size_t)(rowBase + rowl) * HS + colBase;
#pragma unroll
                for (int tj = 0; tj < 4; ++tj) {
                    int coll = wc * 64 + tj * 16 + lr;
                    float z1 = bf2f(Z1[zrow + coll]);
                    smem[rowl * 136 + coll] =
                        f2bf(acc[ti][tj][r] * (1.f - z1 * z1));
                }
            }
        __syncthreads();
        // D[32x8 per wave] = c-rows [wave*32,+32) @ W1T-slice, via 8 MFMAs
        f32x4 dd[2] = {};
#pragma unroll
        for (int h = 0; h < 2; ++h)
#pragma unroll
            for (int kb = 0; kb < 4; ++kb) {
                short8 aF = *(const short8*)(smem + (wave * 32 + h * 16 + lr) * 136
                                             + kb * 32 + lq * 8);
                short8 bF = *(const short8*)(W1T + (size_t)lr * HS + colBase
                                             + kb * 32 + lq * 8);
                dd[h] = __builtin_amdgcn_mfma_f32_16x16x32_bf16(aF, bF, dd[h], 0, 0, 0);
            }
        if (lr < 8) {
#pragma unroll
            for (int h = 0; h < 2; ++h) {
                int row = rowBase + wave * 32 + h * 16 + lq * 4;
#pragma unroll
                for (int rg = 0; rg < 4; ++rg)
                    atomicAdd(&dOut[(size_t)lr * NXS + row + rg], dd[h][rg]);
            }
        }
    }
}

extern "C" void kernel_launch(void* const* d_in, const int* in_sizes, int n_in,
                              void* d_out, int out_size, void* d_ws, size_t ws_size,
                              hipStream_t stream) {
    (void)in_sizes; (void)n_in; (void)out_size; (void)ws_size;
    const float* x  = (const float*)d_in[0];
    const float* W1 = (const float*)d_in[1];
    const float* b1 = (const float*)d_in[2];
    const float* W2 = (const float*)d_in[3];
    const float* b2 = (const float*)d_in[4];
    const float* W3 = (const float*)d_in[5];
    const float* b3 = (const float*)d_in[6];
    float* out = (float*)d_out;

    char* ws = (char*)d_ws;
    // ws layout:
    //   [0, 16MB)     Z1 bf16 (live through GEMM2's epilogue)
    //   [16MB, 32MB)  V bf16
    //   [32MB, 34MB)  Bp1 bf16 fragment-packed W2   (GEMM1 B)
    //   [34MB, 36MB)  Bp2 bf16 fragment-packed W2^T (GEMM2 B)
    //   [36MB, +32KB) W1T bf16 [16][1024] (rows 8..15 zero)
    uint16_t* Z1  = (uint16_t*)(ws);
    uint16_t* V   = (uint16_t*)(ws + (size_t)16 * 1024 * 1024);
    uint16_t* Bp1 = (uint16_t*)(ws + (size_t)32 * 1024 * 1024);
    uint16_t* Bp2 = (uint16_t*)(ws + (size_t)34 * 1024 * 1024);
    uint16_t* W1T = (uint16_t*)(ws + (size_t)36 * 1024 * 1024);

    k01<<<2400, 256, 0, stream>>>(x, W1, b1, W2, b3, Z1, Bp1, Bp2, W1T, out);
    gemm_k<0><<<dim3(NXS / 128, HS / 128), 256, 0, stream>>>(
        Z1, Bp1, b2, W3, V, out, nullptr, nullptr, nullptr);
    gemm_k<1><<<dim3(NXS / 128, HS / 128), 256, 0, stream>>>(
        V, Bp2, nullptr, nullptr, nullptr, nullptr, Z1, W1T, out + NXS);
}